// Round 1
// 223.698 us; speedup vs baseline: 1.0294x; 1.0294x over previous
//
#include <hip/hip_runtime.h>

// Problem constants (from reference)
#define CC 9605
#define BB 2048
#define LL 8
#define CAND_MAX 384
#define NEGF (-1e30f)

// d_ws layout (unsigned words):
//   wsu[0] = wl entry count (atomic)
//   wsu[1] = dtype sniff flags (atomic OR)
//   wsu[4 .. 4+2048) = whitelist entries (col<<8 | mask)
//   byte offset 16384: float partials[BB]
#define WS_PARTIALS_OFF 16384

__device__ __forceinline__ unsigned enc_f(float f) {
  unsigned u = __float_as_uint(f);
  return (u & 0x80000000u) ? ~u : (u | 0x80000000u);
}
__device__ __forceinline__ float dec_u(unsigned e) {
  unsigned u = (e & 0x80000000u) ? (e & 0x7fffffffu) : ~e;
  return __uint_as_float(u);
}
__device__ __forceinline__ float sigm(float z) {
  return 1.0f / (1.0f + __expf(-z));
}

// ---- dtype sniff (word loads): byte signatures over the raw wl buffer ----
//   u8  : byte==1 at offsets %4 != 0        -> flag 1 (and 2)
//   i32 : byte==1 only at offsets %4 == 0   -> flag 2
//   f32 : 0x3f at %4==3, never byte==1      -> flag 8
//   bf16: 0x3f at odd offsets incl %4==1    -> flag 4 (and 8)
__global__ void wl_sniff(const unsigned* __restrict__ wlw,
                         unsigned* __restrict__ wsu) {
  const int nwords = (LL * CC) / 4;  // 76840 % 4 == 0
  const int stride = gridDim.x * blockDim.x;
  unsigned f = 0u;
  for (int j = blockIdx.x * blockDim.x + threadIdx.x; j < nwords; j += stride) {
    unsigned w = wlw[j];
#pragma unroll
    for (int k = 0; k < 4; ++k) {
      unsigned b = (w >> (8 * k)) & 255u;
      if (b == 1u)    { f |= 2u; if (k != 0) f |= 1u; }
      if (b == 0x3fu) { f |= 8u; if (k == 1) f |= 4u; }
    }
  }
#pragma unroll
  for (int off = 32; off >= 1; off >>= 1) f |= __shfl_xor(f, off, 64);
  if ((threadIdx.x & 63) == 0 && f) atomicOr(&wsu[1], f);
}

__global__ void wl_compact(const unsigned char* __restrict__ wl,
                           unsigned* __restrict__ wsu) {
  const int tid = threadIdx.x;
  const int lane = tid & 63;
  const int c = blockIdx.x * 256 + tid;
  const unsigned g = wsu[1];
  const int dt = (g & 1u) ? 0 : (g & 4u) ? 3 : (g & 2u) ? 1 : (g & 8u) ? 2 : 0;
  const int* wl32 = (const int*)wl;
  const float* wlf = (const float*)wl;
  const unsigned short* wlh = (const unsigned short*)wl;
  unsigned m = 0u;
  if (c < CC) {
#pragma unroll
    for (int l = 0; l < LL; ++l) {
      int j = l * CC + c;
      bool on;
      if (dt == 0) on = (wl[j] != 0);
      else if (dt == 1) on = (wl32[j] != 0);
      else if (dt == 2) on = (wlf[j] != 0.0f);
      else on = (wlh[j] != 0);
      if (on) m |= (1u << l);
    }
  }
  unsigned long long bal = __ballot(m != 0u);
  if (bal) {
    unsigned wcnt = (unsigned)__popcll(bal);
    unsigned basep = 0u;
    if (lane == 0) basep = atomicAdd(&wsu[0], wcnt);
    basep = __shfl(basep, 0, 64);
    if (m) {
      unsigned pos = basep + (unsigned)__popcll(bal & ((1ull << lane) - 1ull));
      if (pos < 2048u) wsu[4 + pos] = ((unsigned)c << 8) | m;
    }
  }
}

// Register-resident row: no sh_row staging (LDS 40448B -> ~1.7KB).
// blk_count and candidate compaction operate on the 40 encoded values each
// thread already holds in VGPRs; occupancy goes 4 -> 6 blocks/CU and the
// LDS-latency chains between barriers disappear.
__global__ __launch_bounds__(256, 6) void loss_kernel(
    const float* __restrict__ x, const float* __restrict__ y,
    const unsigned* __restrict__ wsu, float* __restrict__ partials) {
  __shared__ unsigned sh_cand[CAND_MAX];
  __shared__ unsigned sh_redM[4];
  __shared__ unsigned sh_redC[4];
  __shared__ unsigned sh_cnt;
  __shared__ unsigned sh_e11;
  __shared__ float sh_wl[4][10];

  const int tid = threadIdx.x;
  const int lane = tid & 63;
  const int wid = tid >> 6;
  const int b = blockIdx.x;
  const long long base = (long long)b * CC;

  // ---- 1a. issue ALL row loads first (max memory-level parallelism) ----
  const int soff = (4 - (b & 3)) & 3;          // (b*9605 + soff) % 4 == 0
  const int ngroups = (CC - soff) >> 2;        // 2400 or 2401
  const int tailn = CC - soff - (ngroups << 2);
  const int m_extra = soff + tailn;            // <= 6 scalar leftovers
  const float4* vp = (const float4*)(x + base + soff);  // 16B aligned
  float4 t[10];
#pragma unroll
  for (int i = 0; i < 9; ++i) t[i] = vp[tid + (i << 8)];  // g <= 2303 < 2400
  const int g9 = tid + (9 << 8);
  const bool v9 = (g9 < ngroups);
  if (v9) t[9] = vp[g9];
  float tailv = 0.0f;
  const bool has_tail = (tid < m_extra);
  if (has_tail) {
    int tailcol = (tid < soff) ? tid : (soff + (ngroups << 2) + (tid - soff));
    tailv = x[base + tailcol];
  }

  // ---- 1b. issue whitelist gather loads early (latency hides under the
  //          register-only selection phase below) ----
  const unsigned nu = wsu[0];
  const unsigned* ents = wsu + 4;
  unsigned ent0 = 0u, ent1 = 0u;
  float gx0 = NEGF, gy0 = 0.0f, gx1 = NEGF, gy1 = 0.0f;
  const bool h0 = (unsigned)tid < nu;
  const bool h1 = (unsigned)(tid + 256) < nu;
  if (h0) ent0 = ents[tid];
  if (h1) ent1 = ents[tid + 256];
  if (h0) { gx0 = x[base + (ent0 >> 8)]; gy0 = y[base + (ent0 >> 8)]; }
  if (h1) { gx1 = x[base + (ent1 >> 8)]; gy1 = y[base + (ent1 >> 8)]; }

  // ---- 1c. encode IN REGISTERS, track max (no LDS staging) ----
  uint4 u[10];
  unsigned mx = 0u;
#pragma unroll
  for (int i = 0; i < 9; ++i) {
    u[i].x = enc_f(t[i].x); u[i].y = enc_f(t[i].y);
    u[i].z = enc_f(t[i].z); u[i].w = enc_f(t[i].w);
    mx = max(mx, max(max(u[i].x, u[i].y), max(u[i].z, u[i].w)));
  }
  if (v9) {
    u[9].x = enc_f(t[9].x); u[9].y = enc_f(t[9].y);
    u[9].z = enc_f(t[9].z); u[9].w = enc_f(t[9].w);
    mx = max(mx, max(max(u[9].x, u[9].y), max(u[9].z, u[9].w)));
  } else {
    u[9].x = 0u; u[9].y = 0u; u[9].z = 0u; u[9].w = 0u;  // enc 0 < any real
  }
  unsigned et = 0u;
  if (has_tail) { et = enc_f(tailv); mx = max(mx, et); }
  if (tid == 0) sh_cnt = 0u;

  // ---- 2. block max ----
#pragma unroll
  for (int off = 32; off >= 1; off >>= 1) mx = max(mx, __shfl_xor(mx, off, 64));
  if (lane == 0) sh_redM[wid] = mx;
  __syncthreads();
  const unsigned Emax =
      max(max(sh_redM[0], sh_redM[1]), max(sh_redM[2], sh_redM[3]));

  // block count of row >= T, purely from registers (uniform result)
  auto blk_count = [&](unsigned T) -> unsigned {
    unsigned cnt = 0u;
#pragma unroll
    for (int i = 0; i < 10; ++i) {
      cnt += (u[i].x >= T) + (u[i].y >= T) + (u[i].z >= T) + (u[i].w >= T);
    }
    cnt += (et >= T);  // et==0 on non-tail threads, T >= 1
#pragma unroll
    for (int off = 32; off >= 1; off >>= 1) cnt += __shfl_xor(cnt, off, 64);
    __syncthreads();                            // guard sh_redC reuse
    if (lane == 0) sh_redC[wid] = cnt;
    __syncthreads();
    return sh_redC[0] + sh_redC[1] + sh_redC[2] + sh_redC[3];
  };

  // ---- 3. find window [lo,...] holding rank 11 (typ. 1 probe) ----
  unsigned E11 = 0u;
  bool done = false;
  unsigned lo = (Emax > (1u << 23)) ? (Emax - (1u << 23)) : 1u;
  unsigned hi = Emax + 1u;
  unsigned c = blk_count(lo);
  while (c < 11u && lo > 1u) {
    hi = lo;
    lo = (lo > (1u << 23)) ? (lo - (1u << 23)) : 1u;
    c = blk_count(lo);
  }
  while (c > CAND_MAX) {  // rare: bisect (tie-collapse => exact answer)
    if (hi - lo <= 1u) { E11 = lo; done = true; break; }
    unsigned mid = lo + ((hi - lo) >> 1);
    unsigned cm = blk_count(mid);
    if (cm >= 11u) { lo = mid; c = cm; } else { hi = mid; }
  }

  // ---- 4. scan-compact candidates (>= lo) from registers into sh_cand ----
  if (!done) {
    unsigned nloc = 0u;
#pragma unroll
    for (int i = 0; i < 10; ++i) {
      nloc += (u[i].x >= lo) + (u[i].y >= lo) + (u[i].z >= lo) + (u[i].w >= lo);
    }
    nloc += (et >= lo);
    // wave inclusive prefix scan of nloc
    unsigned scan = nloc;
#pragma unroll
    for (int off = 1; off < 64; off <<= 1) {
      unsigned nn = __shfl_up(scan, off, 64);
      if (lane >= off) scan += nn;
    }
    unsigned wtot = __shfl(scan, 63, 64);
    unsigned basep = 0u;
    if (lane == 0) basep = atomicAdd(&sh_cnt, wtot);
    basep = __shfl(basep, 0, 64);
    unsigned pos = basep + scan - nloc;          // exclusive offset
#pragma unroll
    for (int i = 0; i < 10; ++i) {
      if (u[i].x >= lo) sh_cand[pos++] = u[i].x;
      if (u[i].y >= lo) sh_cand[pos++] = u[i].y;
      if (u[i].z >= lo) sh_cand[pos++] = u[i].z;
      if (u[i].w >= lo) sh_cand[pos++] = u[i].w;
    }
    if (et >= lo) sh_cand[pos++] = et;
    __syncthreads();

    // ---- 5. single-wave register top-11 (no barriers, no LDS latency) ----
    if (wid == 0) {
      unsigned v0[6];                           // 6*64 = 384 = CAND_MAX
#pragma unroll
      for (int j = 0; j < 6; ++j) {
        unsigned idx = (unsigned)lane + 64u * j;
        v0[j] = (idx < c) ? sh_cand[idx] : 0u;
      }
      unsigned ans = 0u;
      for (int r = 0; r < 11; ++r) {
        unsigned lmx = v0[0];
#pragma unroll
        for (int j = 1; j < 6; ++j) lmx = max(lmx, v0[j]);
        unsigned wm = lmx;
#pragma unroll
        for (int off = 32; off >= 1; off >>= 1)
          wm = max(wm, __shfl_xor(wm, off, 64));
        ans = wm;
        if (r < 10) {
          unsigned long long bal = __ballot(lmx == wm);
          int first = (int)__ffsll((long long)bal) - 1;
          if (lane == first) {  // remove ONE instance of wm
            bool rm = false;
#pragma unroll
            for (int j = 0; j < 6; ++j) {
              if (!rm && v0[j] == wm) { v0[j] = 0u; rm = true; }
            }
          }
        }
      }
      if (lane == 0) sh_e11 = ans;
    }
    __syncthreads();
    E11 = sh_e11;
  }

  // ---- 6. whitelist gather accumulate (loads issued in 1b, long arrived) ----
  float lm[8];
#pragma unroll
  for (int l = 0; l < 8; ++l) lm[l] = NEGF;
  unsigned pmask = 0u;  // bits0-7: label present; bits8-15: label has positive
  if (h0) {
    unsigned mk = ent0 & 255u;
    pmask |= mk;
    if (gy0 > 0.0f) pmask |= (mk << 8);
#pragma unroll
    for (int l = 0; l < 8; ++l)
      if ((mk >> l) & 1u) lm[l] = fmaxf(lm[l], gx0);
  }
  if (h1) {
    unsigned mk = ent1 & 255u;
    pmask |= mk;
    if (gy1 > 0.0f) pmask |= (mk << 8);
#pragma unroll
    for (int l = 0; l < 8; ++l)
      if ((mk >> l) & 1u) lm[l] = fmaxf(lm[l], gx1);
  }
  // safety net (nu <= 400 in this problem; loop normally never runs)
  for (unsigned e = (unsigned)tid + 512u; e < nu; e += 256u) {
    unsigned ent = ents[e];
    unsigned mk = ent & 255u;
    float xv = x[base + (ent >> 8)];
    float yv = y[base + (ent >> 8)];
    pmask |= mk;
    if (yv > 0.0f) pmask |= (mk << 8);
#pragma unroll
    for (int l = 0; l < 8; ++l)
      if ((mk >> l) & 1u) lm[l] = fmaxf(lm[l], xv);
  }
#pragma unroll
  for (int off = 32; off >= 1; off >>= 1) {
    pmask |= __shfl_xor(pmask, off, 64);
#pragma unroll
    for (int l = 0; l < 8; ++l) lm[l] = fmaxf(lm[l], __shfl_xor(lm[l], off, 64));
  }
  if (lane == 0) {
#pragma unroll
    for (int l = 0; l < 8; ++l) sh_wl[wid][l] = lm[l];
    sh_wl[wid][8] = __uint_as_float(pmask);
  }
  __syncthreads();

  // ---- 7. epilogue on thread 0: per-row partial (no fences, no atomics) ----
  if (tid == 0) {
    float LM[8];
    unsigned PM = 0u;
#pragma unroll
    for (int l = 0; l < 8; ++l) LM[l] = NEGF;
    for (int w = 0; w < 4; ++w) {
#pragma unroll
      for (int l = 0; l < 8; ++l) LM[l] = fmaxf(LM[l], sh_wl[w][l]);
      PM |= __float_as_uint(sh_wl[w][8]);
    }
    unsigned PR = PM & 255u, PO = (PM >> 8) & 255u;
    float thres = fmaxf(sigm(dec_u(E11)), 0.5f);
    float cmax = NEGF, imax = NEGF, umax = NEGF;
#pragma unroll
    for (int l = 0; l < 8; ++l) {
      if ((PR >> l) & 1u) {
        float ml = sigm(LM[l]);
        umax = fmaxf(umax, ml);
        if ((PO >> l) & 1u) cmax = fmaxf(cmax, ml);
        else imax = fmaxf(imax, ml);
      }
    }
    bool anyc = (PO != 0u);
    bool anyi = (PO != 255u);  // L == 8 labels always exist
    float x1 = anyc ? cmax : thres;
    float x2 = anyc ? (anyi ? fmaxf(imax, thres) : thres)
                    : ((nu > 0u) ? umax : NEGF);
    float coef = anyc ? 1.0f : 0.5f;
    float dd = x2 - x1 + 0.1f;
    float rank = ((dd > 0.0f) ? 2.0f : 1.0f) * sigm(10.0f * dd);
    partials[b] = coef * rank;
  }
}

__global__ void final_reduce(const float* __restrict__ partials,
                             float* __restrict__ out) {
  __shared__ float sh[4];
  const int tid = threadIdx.x;
  const int lane = tid & 63;
  const int wid = tid >> 6;
  float s = 0.0f;
  for (int i = tid; i < BB; i += 256) s += partials[i];
#pragma unroll
  for (int off = 32; off >= 1; off >>= 1) s += __shfl_xor(s, off, 64);
  if (lane == 0) sh[wid] = s;
  __syncthreads();
  if (tid == 0) out[0] = (sh[0] + sh[1] + sh[2] + sh[3]) * (1.0f / (float)BB);
}

extern "C" void kernel_launch(void* const* d_in, const int* in_sizes, int n_in,
                              void* d_out, int out_size, void* d_ws,
                              size_t ws_size, hipStream_t stream) {
  const float* x = (const float*)d_in[0];
  const float* y = (const float*)d_in[1];
  // d_in[2] (y_neg) is faithfully ignored — it never affects the loss.
  const unsigned char* wl = (const unsigned char*)d_in[3];
  float* out = (float*)d_out;
  unsigned* wsu = (unsigned*)d_ws;
  float* partials = (float*)((char*)d_ws + WS_PARTIALS_OFF);

  hipMemsetAsync(d_ws, 0, 16, stream);  // zero wsu[0..3]
  wl_sniff<<<64, 256, 0, stream>>>((const unsigned*)wl, wsu);
  wl_compact<<<(CC + 255) / 256, 256, 0, stream>>>(wl, wsu);
  loss_kernel<<<BB, 256, 0, stream>>>(x, y, wsu, partials);
  final_reduce<<<1, 256, 0, stream>>>(partials, out);
}